// Round 4
// baseline (722.116 us; speedup 1.0000x reference)
//
#include <hip/hip_runtime.h>

// LinearCrossAttention: B=8, N=T=4096, C=512, H=8, d=64, 3 terms.
// R4: unified GEMM template — f32 A staged directly (no cvt passes),
// K/V stacked in column space (single acc, better occupancy), LDS-repacked
// coalesced bf16 stores.

#define B_  8
#define N_  4096
#define C_  512
#define T_  4096
#define H_  8
#define M_  (B_*N_)   // 32768

typedef __bf16 bf16_8 __attribute__((ext_vector_type(8)));
typedef float  f32_4  __attribute__((ext_vector_type(4)));

__device__ __forceinline__ unsigned short f2bf(float f) {
  unsigned u = __float_as_uint(f);
  unsigned r = 0x7FFFu + ((u >> 16) & 1u);
  return (unsigned short)((u + r) >> 16);
}
__device__ __forceinline__ float bf2f(unsigned short h) {
  return __uint_as_float(((unsigned)h) << 16);
}

__device__ __forceinline__ void gload16(const void* g, void* l) {
  __builtin_amdgcn_global_load_lds(
      (const __attribute__((address_space(1))) unsigned int*)g,
      (__attribute__((address_space(3))) unsigned int*)l, 16, 0, 0);
}

// ---------------- f32 -> bf16 conversion (weights only now) -----------------
__global__ __launch_bounds__(256) void cvt_f32_bf16(
    const float* __restrict__ in, unsigned short* __restrict__ out, long n4)
{
  long i = (long)blockIdx.x * blockDim.x + threadIdx.x;
  long stride = (long)gridDim.x * blockDim.x;
  for (; i < n4; i += stride) {
    float4 v = ((const float4*)in)[i];
    ushort4 o;
    o.x = f2bf(v.x); o.y = f2bf(v.y); o.z = f2bf(v.z); o.w = f2bf(v.w);
    ((ushort4*)out)[i] = o;
  }
}

// ---------------- unified GEMM --------------------------------------------
// C[m,n] = sum_k A[m,k]*W[n,k] + bias[n]; A row stride = 512, out row stride 512.
// EPI: 0 = f32 out (final proj), 1 = softmax->bf16 (q), 2 = kv (softmax on K half)
// ADT: 0 = A is f32 (convert during fragment load), 1 = A is bf16
template<int EPI, int ADT>
__global__ __launch_bounds__(256) void gemm_all(
    const void* __restrict__ Av,
    const unsigned short* __restrict__ Bw,   // [N][512] bf16
    const float* __restrict__ biasK,
    const float* __restrict__ biasV,
    void* __restrict__ outK,
    void* __restrict__ outV)
{
  __shared__ char smem[49152];
  float* sAf = (float*)smem;                               // ADT=0: 32 KB
  unsigned short* sAh = (unsigned short*)smem;             // ADT=1: 16 KB
  unsigned short* sBw = (unsigned short*)(smem + 32768);   // 16 KB

  const int tid = threadIdx.x, lane = tid & 63, wid = tid >> 6;
  const int wr = wid >> 1, wc = wid & 1;
  const int l15 = lane & 15, l16 = lane >> 4;
  const size_t row0 = (size_t)blockIdx.x * 128;
  const int col0 = blockIdx.y * 128;

  f32_4 acc[4][4] = {};
  for (int k0 = 0; k0 < 512; k0 += 64) {
    if constexpr (ADT == 0) {
      const float* A = (const float*)Av;
#pragma unroll
      for (int j = 0; j < 8; ++j) {
        int c = j*256 + tid, row = c >> 4, c16 = c & 15;
        gload16(A + (row0 + row)*512 + k0 + c16*4, smem + (size_t)(j*256 + wid*64)*16);
      }
    } else {
      const unsigned short* A = (const unsigned short*)Av;
#pragma unroll
      for (int j = 0; j < 4; ++j) {
        int c = j*256 + tid, row = c >> 3, c8 = c & 7;
        gload16(A + (row0 + row)*512 + k0 + c8*8, smem + (size_t)(j*256 + wid*64)*16);
      }
    }
#pragma unroll
    for (int j = 0; j < 4; ++j) {
      int c = j*256 + tid, row = c >> 3, c8 = c & 7;
      gload16(Bw + (size_t)(col0 + row)*512 + k0 + c8*8,
              smem + 32768 + (size_t)(j*256 + wid*64)*16);
    }
    __syncthreads();
#pragma unroll
    for (int kk = 0; kk < 64; kk += 32) {
      bf16_8 af[4], bfr[4];
#pragma unroll
      for (int mi = 0; mi < 4; ++mi) {
        if constexpr (ADT == 0) {
          const float* p = &sAf[(wr*64 + mi*16 + l15)*64 + kk + l16*8];
          f32_4 lo = *(const f32_4*)p, hi = *(const f32_4*)(p + 4);
          bf16_8 a;
#pragma unroll
          for (int e = 0; e < 4; ++e) { a[e] = (__bf16)lo[e]; a[e+4] = (__bf16)hi[e]; }
          af[mi] = a;
        } else {
          af[mi] = *(const bf16_8*)&sAh[(wr*64 + mi*16 + l15)*64 + kk + l16*8];
        }
      }
#pragma unroll
      for (int ni = 0; ni < 4; ++ni)
        bfr[ni] = *(const bf16_8*)&sBw[(wc*64 + ni*16 + l15)*64 + kk + l16*8];
#pragma unroll
      for (int mi = 0; mi < 4; ++mi)
#pragma unroll
        for (int ni = 0; ni < 4; ++ni)
          acc[mi][ni] = __builtin_amdgcn_mfma_f32_16x16x32_bf16(af[mi], bfr[ni], acc[mi][ni], 0, 0, 0);
    }
    __syncthreads();
  }

  // ---- epilogue ----
  if constexpr (EPI == 0) {
    float* Cf = (float*)outK;
#pragma unroll
    for (int mi = 0; mi < 4; ++mi) {
      int rb = wr*64 + mi*16 + l16*4;
#pragma unroll
      for (int ni = 0; ni < 4; ++ni) {
        int col = col0 + wc*64 + ni*16 + l15;
        float bv = biasK[col];
#pragma unroll
        for (int jj = 0; jj < 4; ++jj)
          Cf[(row0 + rb + jj)*512 + col] = acc[mi][ni][jj] + bv;
      }
    }
    return;
  } else {
    const bool dosm = (EPI == 1) || (EPI == 2 && blockIdx.y < 4);
    unsigned short* ob;
    int oc0;
    if constexpr (EPI == 1) { ob = (unsigned short*)outK; oc0 = col0; }
    else {
      if (blockIdx.y < 4) { ob = (unsigned short*)outK; oc0 = col0; }
      else                { ob = (unsigned short*)outV; oc0 = col0 - 512; }
    }
    float bvv[4];
#pragma unroll
    for (int ni = 0; ni < 4; ++ni) {
      int colg = col0 + wc*64 + ni*16 + l15;
      if constexpr (EPI == 1) bvv[ni] = biasK[colg];
      else bvv[ni] = (blockIdx.y < 4) ? biasK[colg] : biasV[colg - 512];
    }
    unsigned short* sE = (unsigned short*)smem;   // 128 x pitch 136 (34.8 KB)
#pragma unroll
    for (int mi = 0; mi < 4; ++mi) {
#pragma unroll
      for (int jj = 0; jj < 4; ++jj) {
        float x[4];
#pragma unroll
        for (int ni = 0; ni < 4; ++ni) x[ni] = acc[mi][ni][jj] + bvv[ni];
        if (dosm) {
          float m = fmaxf(fmaxf(x[0], x[1]), fmaxf(x[2], x[3]));
#pragma unroll
          for (int o = 8; o; o >>= 1) m = fmaxf(m, __shfl_xor(m, o));
          float s = 0.f;
#pragma unroll
          for (int ni = 0; ni < 4; ++ni) { x[ni] = __expf(x[ni] - m); s += x[ni]; }
#pragma unroll
          for (int o = 8; o; o >>= 1) s += __shfl_xor(s, o);
          float inv = 1.0f / s;
#pragma unroll
          for (int ni = 0; ni < 4; ++ni) x[ni] *= inv;
        }
        int r = wr*64 + mi*16 + l16*4 + jj;
#pragma unroll
        for (int ni = 0; ni < 4; ++ni)
          sE[r*136 + wc*64 + ni*16 + l15] = f2bf(x[ni]);
      }
    }
    __syncthreads();
    int r = tid >> 1, seg = tid & 1;
    unsigned short* orow = ob + (row0 + r)*512 + oc0 + seg*64;
#pragma unroll
    for (int u = 0; u < 8; ++u)
      *(uint4*)(orow + u*8) = *(const uint4*)&sE[r*136 + seg*64 + u*8];
  }
}

// ---------------- ctx: ctxT[bh][dv][e] += sum_t k[t][e]*v[t][dv]; kc += sum_t k
__global__ __launch_bounds__(256) void ctx_kernel(
    const unsigned short* __restrict__ k, const unsigned short* __restrict__ v,
    float* __restrict__ ctxT,  // [64bh][64dv][64e]
    float* __restrict__ kc)    // [64bh][64e]
{
  __shared__ unsigned short kT[64*136];
  __shared__ unsigned short vT[64*136];
  const int tid = threadIdx.x;
  const int lane = tid & 63, wid = tid >> 6;
  const int wr = wid >> 1, wc = wid & 1;
  const int l15 = lane & 15, l16 = lane >> 4;
  const int bh = blockIdx.y, b = bh >> 3, h = bh & 7;
  const int t0 = blockIdx.x * 512;

  f32_4 acc[2][2] = {};
  float kcacc = 0.f;
  const int kcd = tid & 63, kcq = tid >> 6;

  for (int tt = 0; tt < 4; ++tt) {
    const size_t gbase = ((size_t)b*T_ + t0 + tt*128)*C_ + h*64;
#pragma unroll
    for (int it = 0; it < 8; ++it) {
      int c = it*256 + tid;
      int c2 = c & 1023;
      int t = c2 >> 3, d0 = (c2 & 7)*8;
      const unsigned short* src = ((c < 1024) ? k : v) + gbase + (size_t)t*C_ + d0;
      unsigned short* dst = (c < 1024) ? kT : vT;
      uint4 w = *(const uint4*)src;
      dst[(d0+0)*136 + t] = (unsigned short)(w.x & 0xffff);
      dst[(d0+1)*136 + t] = (unsigned short)(w.x >> 16);
      dst[(d0+2)*136 + t] = (unsigned short)(w.y & 0xffff);
      dst[(d0+3)*136 + t] = (unsigned short)(w.y >> 16);
      dst[(d0+4)*136 + t] = (unsigned short)(w.z & 0xffff);
      dst[(d0+5)*136 + t] = (unsigned short)(w.z >> 16);
      dst[(d0+6)*136 + t] = (unsigned short)(w.w & 0xffff);
      dst[(d0+7)*136 + t] = (unsigned short)(w.w >> 16);
    }
    __syncthreads();
#pragma unroll
    for (int s = 0; s < 32; ++s)
      kcacc += bf2f(kT[kcd*136 + kcq*32 + s]);
#pragma unroll
    for (int ks = 0; ks < 4; ++ks) {
      bf16_8 af[2], bfr[2];
#pragma unroll
      for (int mi = 0; mi < 2; ++mi)
        af[mi] = *(const bf16_8*)&kT[(wr*32 + mi*16 + l15)*136 + ks*32 + l16*8];
#pragma unroll
      for (int ni = 0; ni < 2; ++ni)
        bfr[ni] = *(const bf16_8*)&vT[(wc*32 + ni*16 + l15)*136 + ks*32 + l16*8];
#pragma unroll
      for (int mi = 0; mi < 2; ++mi)
#pragma unroll
        for (int ni = 0; ni < 2; ++ni)
          acc[mi][ni] = __builtin_amdgcn_mfma_f32_16x16x32_bf16(af[mi], bfr[ni], acc[mi][ni], 0, 0, 0);
    }
    __syncthreads();
  }

  float* cbase = ctxT + (size_t)bh * 64*64;
#pragma unroll
  for (int mi = 0; mi < 2; ++mi)
#pragma unroll
    for (int ni = 0; ni < 2; ++ni)
#pragma unroll
      for (int jj = 0; jj < 4; ++jj) {
        int dk = wr*32 + mi*16 + l16*4 + jj;   // e index
        int dv = wc*32 + ni*16 + l15;          // v index
        atomicAdd(cbase + dv*64 + dk, acc[mi][ni][jj]);
      }
  atomicAdd(kc + (size_t)bh*64 + kcd, kcacc);
}

// ---------------- combine (MFMA): out = q + sum_i (q@ctx_i)/(q.kc_i) --------
__global__ __launch_bounds__(256) void combine2(
    const unsigned short* __restrict__ qb,
    const float* __restrict__ ctxT,          // [3][64bh][64dv][64e]
    const float* __restrict__ kc,            // [3][64bh][64e]
    unsigned short* __restrict__ outp)
{
  __shared__ unsigned short sQ[128*64];
  __shared__ unsigned short sB[208*64];
  __shared__ float sS[128*3];
  const int tid = threadIdx.x, lane = tid & 63, wid = tid >> 6;
  const int l15 = lane & 15, l16 = lane >> 4;
  const int bh = blockIdx.y, b = bh >> 3, h = bh & 7;
  const int n0 = blockIdx.x * 128;
  const size_t qbase = ((size_t)b*N_ + n0)*C_ + h*64;

#pragma unroll
  for (int j = 0; j < 4; ++j) {
    int c = j*256 + tid;
    int row = c >> 3, c8 = c & 7;
    gload16(qb + qbase + (size_t)row*C_ + c8*8, sQ + (size_t)(j*256 + wid*64)*8);
  }
  for (int f = tid; f < 208*64; f += 256) {
    int col = f >> 6, e = f & 63;
    float val = 0.f;
    if (col < 192)
      val = ctxT[(((size_t)(col >> 6)*64 + bh)*64 + (col & 63))*64 + e];
    else if (col < 195)
      val = kc[((size_t)(col - 192)*64 + bh)*64 + e];
    sB[col*64 + e] = f2bf(val);
  }
  __syncthreads();

  f32_4 acc[2][13] = {};
#pragma unroll
  for (int ks = 0; ks < 2; ++ks) {
    bf16_8 af[2];
#pragma unroll
    for (int mi = 0; mi < 2; ++mi)
      af[mi] = *(const bf16_8*)&sQ[(wid*32 + mi*16 + l15)*64 + ks*32 + l16*8];
#pragma unroll
    for (int ni = 0; ni < 13; ++ni) {
      bf16_8 bfr = *(const bf16_8*)&sB[(ni*16 + l15)*64 + ks*32 + l16*8];
#pragma unroll
      for (int mi = 0; mi < 2; ++mi)
        acc[mi][ni] = __builtin_amdgcn_mfma_f32_16x16x32_bf16(af[mi], bfr, acc[mi][ni], 0, 0, 0);
    }
  }

  if (l15 < 3) {
#pragma unroll
    for (int mi = 0; mi < 2; ++mi)
#pragma unroll
      for (int jj = 0; jj < 4; ++jj)
        sS[(wid*32 + mi*16 + l16*4 + jj)*3 + l15] = acc[mi][12][jj];
  }
  __syncthreads();

#pragma unroll
  for (int mi = 0; mi < 2; ++mi) {
#pragma unroll
    for (int jj = 0; jj < 4; ++jj) {
      int r = wid*32 + mi*16 + l16*4 + jj;
      float inv[3];
#pragma unroll
      for (int i = 0; i < 3; ++i) inv[i] = 1.0f / sS[r*3 + i];
#pragma unroll
      for (int ni = 0; ni < 4; ++ni) {
        int dv = ni*16 + l15;
        float val = bf2f(sQ[r*64 + dv]);
#pragma unroll
        for (int i = 0; i < 3; ++i) val += acc[mi][i*4 + ni][jj] * inv[i];
        outp[qbase + (size_t)r*C_ + dv] = f2bf(val);
      }
    }
  }
}

// ---------------------------------------------------------------------------
extern "C" void kernel_launch(void* const* d_in, const int* in_sizes, int n_in,
                              void* d_out, int out_size, void* d_ws, size_t ws_size,
                              hipStream_t stream)
{
  const float* x  = (const float*)d_in[0];
  const float* y  = (const float*)d_in[1];
  const float* Wq = (const float*)d_in[2];
  const float* bq = (const float*)d_in[3];
  const float* Wk = (const float*)d_in[4];
  const float* bk = (const float*)d_in[5];
  const float* Wv = (const float*)d_in[6];
  const float* bv = (const float*)d_in[7];
  const float* Wp = (const float*)d_in[8];
  const float* bp = (const float*)d_in[9];
  float* out = (float*)d_out;
  char* ws = (char*)d_ws;

  const size_t SZ_BF = (size_t)M_ * C_ * 2;  // 32 MB bf16
  const size_t WCC   = (size_t)C_ * C_;      // 262144

  unsigned short* qb   = (unsigned short*)(ws);
  unsigned short* kb   = (unsigned short*)(ws + 1*SZ_BF);  // also out_pre
  unsigned short* vb   = (unsigned short*)(ws + 2*SZ_BF);
  unsigned short* wq_b = (unsigned short*)(ws + 3*SZ_BF);
  unsigned short* wkv  = wq_b + WCC;                        // 3 * [1024][512]
  unsigned short* wp_b = wkv + 6*WCC;
  float* ctxT = (float*)(wp_b + WCC);
  float* kc   = ctxT + (size_t)3*64*64*64;

  // weight conversions
  cvt_f32_bf16<<<256, 256, 0, stream>>>(Wq, wq_b, (long)WCC/4);
  for (int i = 0; i < 3; ++i) {
    cvt_f32_bf16<<<256, 256, 0, stream>>>(Wk + i*WCC, wkv + (size_t)i*2*WCC,       (long)WCC/4);
    cvt_f32_bf16<<<256, 256, 0, stream>>>(Wv + i*WCC, wkv + (size_t)i*2*WCC + WCC, (long)WCC/4);
  }
  cvt_f32_bf16<<<256, 256, 0, stream>>>(Wp, wp_b, (long)WCC/4);

  hipMemsetAsync(ctxT, 0, ((size_t)3*64*64*64 + (size_t)3*64*64) * sizeof(float), stream);

  // q = softmax(x @ Wq^T + bq)
  gemm_all<1,0><<<dim3(M_/128, 4), 256, 0, stream>>>(x, wq_b, bq, nullptr, qb, nullptr);

  for (int i = 0; i < 3; ++i) {
    gemm_all<2,0><<<dim3(M_/128, 8), 256, 0, stream>>>(
        y + (size_t)i*M_*C_, wkv + (size_t)i*2*WCC,
        bk + i*C_, bv + i*C_, kb, vb);
    ctx_kernel<<<dim3(8, 64), 256, 0, stream>>>(kb, vb,
        ctxT + (size_t)i*64*64*64, kc + (size_t)i*64*64);
  }

  combine2<<<dim3(32, 64), 256, 0, stream>>>(qb, ctxT, kc, kb);
  gemm_all<0,1><<<dim3(M_/128, 4), 256, 0, stream>>>(kb, wp_b, bp, nullptr, out, nullptr);
}

// Round 5
// 676.706 us; speedup vs baseline: 1.0671x; 1.0671x over previous
//
#include <hip/hip_runtime.h>

// LinearCrossAttention: B=8, N=T=4096, C=512, H=8, d=64, 3 terms.
// R5: T2 XOR chunk-swizzle on all LDS staging (kills 16-way bank conflicts);
// ctx+kc fused into the K/V GEMM (k/v never written to HBM).

#define B_  8
#define N_  4096
#define C_  512
#define T_  4096
#define H_  8
#define M_  (B_*N_)   // 32768

typedef __bf16 bf16_8 __attribute__((ext_vector_type(8)));
typedef float  f32_4  __attribute__((ext_vector_type(4)));

__device__ __forceinline__ unsigned short f2bf(float f) {
  unsigned u = __float_as_uint(f);
  unsigned r = 0x7FFFu + ((u >> 16) & 1u);
  return (unsigned short)((u + r) >> 16);
}
__device__ __forceinline__ float bf2f(unsigned short h) {
  return __uint_as_float(((unsigned)h) << 16);
}

__device__ __forceinline__ void gload16(const void* g, void* l) {
  __builtin_amdgcn_global_load_lds(
      (const __attribute__((address_space(1))) unsigned int*)g,
      (__attribute__((address_space(3))) unsigned int*)l, 16, 0, 0);
}

// ---------------- f32 -> bf16 conversion (weights only) ---------------------
__global__ __launch_bounds__(256) void cvt_f32_bf16(
    const float* __restrict__ in, unsigned short* __restrict__ out, long n4)
{
  long i = (long)blockIdx.x * blockDim.x + threadIdx.x;
  long stride = (long)gridDim.x * blockDim.x;
  for (; i < n4; i += stride) {
    float4 v = ((const float4*)in)[i];
    ushort4 o;
    o.x = f2bf(v.x); o.y = f2bf(v.y); o.z = f2bf(v.z); o.w = f2bf(v.w);
    ((ushort4*)out)[i] = o;
  }
}

// ---------------- unified GEMM (q path EPI=1, final EPI=0) ------------------
// EPI: 0 = f32 out + bias.  1 = softmax->bf16 (q path).
// ADT: 0 = A f32 (convert at fragment load), 1 = A bf16.
template<int EPI, int ADT>
__global__ __launch_bounds__(256) void gemm_all(
    const void* __restrict__ Av,
    const unsigned short* __restrict__ Bw,   // [N][512] bf16
    const float* __restrict__ bias,
    void* __restrict__ outp)
{
  __shared__ char smem[49152];
  float* sAf = (float*)smem;                               // ADT=0: 32 KB
  unsigned short* sAh = (unsigned short*)smem;             // ADT=1: 16 KB
  unsigned short* sBw = (unsigned short*)(smem + 32768);   // 16 KB

  const int tid = threadIdx.x, lane = tid & 63, wid = tid >> 6;
  const int wr = wid >> 1, wc = wid & 1;
  const int l15 = lane & 15, l16 = lane >> 4;
  const size_t row0 = (size_t)blockIdx.x * 128;
  const int col0 = blockIdx.y * 128;

  f32_4 acc[4][4] = {};
  for (int k0 = 0; k0 < 512; k0 += 64) {
    if constexpr (ADT == 0) {
      const float* A = (const float*)Av;
#pragma unroll
      for (int j = 0; j < 8; ++j) {
        int c = j*256 + tid, row = c >> 4, s = c & 15;
        gload16(A + (row0 + row)*512 + k0 + ((s ^ (row & 15)) << 2),
                smem + (size_t)(j*256 + wid*64)*16);
      }
    } else {
      const unsigned short* A = (const unsigned short*)Av;
#pragma unroll
      for (int j = 0; j < 4; ++j) {
        int c = j*256 + tid, row = c >> 3, s = c & 7;
        gload16(A + (row0 + row)*512 + k0 + ((s ^ (row & 7)) << 3),
                smem + (size_t)(j*256 + wid*64)*16);
      }
    }
#pragma unroll
    for (int j = 0; j < 4; ++j) {
      int c = j*256 + tid, row = c >> 3, s = c & 7;
      gload16(Bw + (size_t)(col0 + row)*512 + k0 + ((s ^ (row & 7)) << 3),
              smem + 32768 + (size_t)(j*256 + wid*64)*16);
    }
    __syncthreads();
#pragma unroll
    for (int kk = 0; kk < 64; kk += 32) {
      bf16_8 af[4], bfr[4];
#pragma unroll
      for (int mi = 0; mi < 4; ++mi) {
        int r = wr*64 + mi*16 + l15;
        if constexpr (ADT == 0) {
          int ch0 = (kk + l16*8) >> 2;         // even
          const float* base = &sAf[r*64];
          f32_4 lo = *(const f32_4*)&base[((ch0    ) ^ (r & 15)) << 2];
          f32_4 hi = *(const f32_4*)&base[((ch0 + 1) ^ (r & 15)) << 2];
          bf16_8 a;
#pragma unroll
          for (int e = 0; e < 4; ++e) { a[e] = (__bf16)lo[e]; a[e+4] = (__bf16)hi[e]; }
          af[mi] = a;
        } else {
          int ch = (kk >> 3) + l16;
          af[mi] = *(const bf16_8*)&sAh[r*64 + ((ch ^ (r & 7)) << 3)];
        }
      }
#pragma unroll
      for (int ni = 0; ni < 4; ++ni) {
        int r = wc*64 + ni*16 + l15;
        int ch = (kk >> 3) + l16;
        bfr[ni] = *(const bf16_8*)&sBw[r*64 + ((ch ^ (r & 7)) << 3)];
      }
#pragma unroll
      for (int mi = 0; mi < 4; ++mi)
#pragma unroll
        for (int ni = 0; ni < 4; ++ni)
          acc[mi][ni] = __builtin_amdgcn_mfma_f32_16x16x32_bf16(af[mi], bfr[ni], acc[mi][ni], 0, 0, 0);
    }
    __syncthreads();
  }

  if constexpr (EPI == 0) {
    float* Cf = (float*)outp;
#pragma unroll
    for (int mi = 0; mi < 4; ++mi) {
      int rb = wr*64 + mi*16 + l16*4;
#pragma unroll
      for (int ni = 0; ni < 4; ++ni) {
        int col = col0 + wc*64 + ni*16 + l15;
        float bv = bias[col];
#pragma unroll
        for (int jj = 0; jj < 4; ++jj)
          Cf[(row0 + rb + jj)*512 + col] = acc[mi][ni][jj] + bv;
      }
    }
  } else {
    unsigned short* ob = (unsigned short*)outp;
    float bvv[4];
#pragma unroll
    for (int ni = 0; ni < 4; ++ni) bvv[ni] = bias[col0 + wc*64 + ni*16 + l15];
    unsigned short* sE = (unsigned short*)smem;   // 128 x pitch 136
#pragma unroll
    for (int mi = 0; mi < 4; ++mi) {
#pragma unroll
      for (int jj = 0; jj < 4; ++jj) {
        float x[4];
#pragma unroll
        for (int ni = 0; ni < 4; ++ni) x[ni] = acc[mi][ni][jj] + bvv[ni];
        float m = fmaxf(fmaxf(x[0], x[1]), fmaxf(x[2], x[3]));
#pragma unroll
        for (int o = 8; o; o >>= 1) m = fmaxf(m, __shfl_xor(m, o));
        float s = 0.f;
#pragma unroll
        for (int ni = 0; ni < 4; ++ni) { x[ni] = __expf(x[ni] - m); s += x[ni]; }
#pragma unroll
        for (int o = 8; o; o >>= 1) s += __shfl_xor(s, o);
        float inv = 1.0f / s;
        int r = wr*64 + mi*16 + l16*4 + jj;
#pragma unroll
        for (int ni = 0; ni < 4; ++ni)
          sE[r*136 + wc*64 + ni*16 + l15] = f2bf(x[ni] * inv);
      }
    }
    __syncthreads();
    int r = tid >> 1, seg = tid & 1;
    unsigned short* orow = ob + (row0 + r)*512 + col0 + seg*64;
#pragma unroll
    for (int u = 0; u < 8; ++u)
      *(uint4*)(orow + u*8) = *(const uint4*)&sE[r*136 + seg*64 + u*8];
  }
}

// ---------------- fused K/V GEMM + softmax + ctx/kc -------------------------
// grid (64, 8): block = 512 rows (4 chunks of 128) x head h.
// Per chunk: GEMM 128x128 (cols 0..63 = K head-seg, 64..127 = V head-seg),
// softmax K, write K^T/V^T to LDS, accumulate ctx MFMA in regs; atomics once.
__global__ __launch_bounds__(256) void kvctx_kernel(
    const float* __restrict__ y,             // (B,T,512) f32 slice for term i
    const unsigned short* __restrict__ Wk_b, // [512][512] bf16
    const unsigned short* __restrict__ Wv_b,
    const float* __restrict__ bk, const float* __restrict__ bv,
    float* __restrict__ ctxT,                // [64bh][64dv][64e] slice
    float* __restrict__ kc)                  // [64bh][64e] slice
{
  __shared__ char smem[49152];
  float* sAf = (float*)smem;                              // 32 KB staging
  unsigned short* sBw = (unsigned short*)(smem + 32768);  // 16 KB
  unsigned short* sKT = (unsigned short*)smem;            // 64*136*2 = 17408 B
  unsigned short* sVT = (unsigned short*)(smem + 17408);  // 17408 B

  const int tid = threadIdx.x, lane = tid & 63, wid = tid >> 6;
  const int wr = wid >> 1, wc = wid & 1;
  const int l15 = lane & 15, l16 = lane >> 4;
  const int h = blockIdx.y;
  const int bx = blockIdx.x;                 // 0..63
  const int b = bx >> 3;                     // 512-row blocks: 8 per batch
  const int bh = b*8 + h;

  f32_4 cacc[2][2] = {};
  float kcp[4] = {0.f, 0.f, 0.f, 0.f};

  for (int chunk = 0; chunk < 4; ++chunk) {
    const size_t row0 = (size_t)bx*512 + chunk*128;
    f32_4 acc[4][4] = {};
    for (int k0 = 0; k0 < 512; k0 += 64) {
#pragma unroll
      for (int j = 0; j < 8; ++j) {
        int c = j*256 + tid, row = c >> 4, s = c & 15;
        gload16(y + (row0 + row)*512 + k0 + ((s ^ (row & 15)) << 2),
                smem + (size_t)(j*256 + wid*64)*16);
      }
#pragma unroll
      for (int j = 0; j < 4; ++j) {
        int c = j*256 + tid, row = c >> 3, s = c & 7;
        const unsigned short* wsrc = (row < 64)
            ? Wk_b + (size_t)(h*64 + row)*512
            : Wv_b + (size_t)(h*64 + row - 64)*512;
        gload16(wsrc + k0 + ((s ^ (row & 7)) << 3),
                smem + 32768 + (size_t)(j*256 + wid*64)*16);
      }
      __syncthreads();
#pragma unroll
      for (int kk = 0; kk < 64; kk += 32) {
        bf16_8 af[4], bfr[4];
#pragma unroll
        for (int mi = 0; mi < 4; ++mi) {
          int r = wr*64 + mi*16 + l15;
          int ch0 = (kk + l16*8) >> 2;
          const float* base = &sAf[r*64];
          f32_4 lo = *(const f32_4*)&base[((ch0    ) ^ (r & 15)) << 2];
          f32_4 hi = *(const f32_4*)&base[((ch0 + 1) ^ (r & 15)) << 2];
          bf16_8 a;
#pragma unroll
          for (int e = 0; e < 4; ++e) { a[e] = (__bf16)lo[e]; a[e+4] = (__bf16)hi[e]; }
          af[mi] = a;
        }
#pragma unroll
        for (int ni = 0; ni < 4; ++ni) {
          int r = wc*64 + ni*16 + l15;
          int ch = (kk >> 3) + l16;
          bfr[ni] = *(const bf16_8*)&sBw[r*64 + ((ch ^ (r & 7)) << 3)];
        }
#pragma unroll
        for (int mi = 0; mi < 4; ++mi)
#pragma unroll
          for (int ni = 0; ni < 4; ++ni)
            acc[mi][ni] = __builtin_amdgcn_mfma_f32_16x16x32_bf16(af[mi], bfr[ni], acc[mi][ni], 0, 0, 0);
      }
      __syncthreads();
    }

    // epilogue: K waves (wc==0) softmax + transposed store + kc partials;
    // V waves (wc==1) bias + transposed store. (safe: all waves past last sync)
    if (wc == 0) {
      float bkv[4];
#pragma unroll
      for (int ni = 0; ni < 4; ++ni) bkv[ni] = bk[h*64 + ni*16 + l15];
#pragma unroll
      for (int mi = 0; mi < 4; ++mi) {
#pragma unroll
        for (int jj = 0; jj < 4; ++jj) {
          float x[4];
#pragma unroll
          for (int ni = 0; ni < 4; ++ni) x[ni] = acc[mi][ni][jj] + bkv[ni];
          float m = fmaxf(fmaxf(x[0], x[1]), fmaxf(x[2], x[3]));
#pragma unroll
          for (int o = 8; o; o >>= 1) m = fmaxf(m, __shfl_xor(m, o));
          float s = 0.f;
#pragma unroll
          for (int ni = 0; ni < 4; ++ni) { x[ni] = __expf(x[ni] - m); s += x[ni]; }
#pragma unroll
          for (int o = 8; o; o >>= 1) s += __shfl_xor(s, o);
          float inv = 1.0f / s;
          int r = wr*64 + mi*16 + l16*4 + jj;
#pragma unroll
          for (int ni = 0; ni < 4; ++ni) {
            float kv = x[ni] * inv;
            kcp[ni] += kv;
            sKT[(ni*16 + l15)*136 + r] = f2bf(kv);
          }
        }
      }
    } else {
      float bvv[4];
#pragma unroll
      for (int ni = 0; ni < 4; ++ni) bvv[ni] = bv[h*64 + ni*16 + l15];
#pragma unroll
      for (int mi = 0; mi < 4; ++mi) {
#pragma unroll
        for (int jj = 0; jj < 4; ++jj) {
          int r = wr*64 + mi*16 + l16*4 + jj;
#pragma unroll
          for (int ni = 0; ni < 4; ++ni)
            sVT[(ni*16 + l15)*136 + r] = f2bf(acc[mi][ni][jj] + bvv[ni]);
        }
      }
    }
    __syncthreads();

    // ctx partial: cacc[e][dv] += sum_t k[t][e] * v[t][dv], K = 128 rows
#pragma unroll
    for (int ks = 0; ks < 4; ++ks) {
      bf16_8 a2[2], b2[2];
#pragma unroll
      for (int mi = 0; mi < 2; ++mi)
        a2[mi] = *(const bf16_8*)&sKT[(wr*32 + mi*16 + l15)*136 + ks*32 + l16*8];
#pragma unroll
      for (int ni = 0; ni < 2; ++ni)
        b2[ni] = *(const bf16_8*)&sVT[(wc*32 + ni*16 + l15)*136 + ks*32 + l16*8];
#pragma unroll
      for (int mi = 0; mi < 2; ++mi)
#pragma unroll
        for (int ni = 0; ni < 2; ++ni)
          cacc[mi][ni] = __builtin_amdgcn_mfma_f32_16x16x32_bf16(a2[mi], b2[ni], cacc[mi][ni], 0, 0, 0);
    }
    __syncthreads();
  }

  // kc: reduce kcp over row-groups (lane bits 4,5) then atomic per wave
  if (wc == 0) {
#pragma unroll
    for (int ni = 0; ni < 4; ++ni) {
      float s = kcp[ni];
      s += __shfl_xor(s, 16);
      s += __shfl_xor(s, 32);
      if (l16 == 0) atomicAdd(kc + (size_t)bh*64 + ni*16 + l15, s);
    }
  }
  // ctx: atomicAdd quadrant (e = wr*32.., dv = wc*32..)
  float* cbase = ctxT + (size_t)bh * 64*64;
#pragma unroll
  for (int mi = 0; mi < 2; ++mi)
#pragma unroll
    for (int ni = 0; ni < 2; ++ni)
#pragma unroll
      for (int jj = 0; jj < 4; ++jj) {
        int e  = wr*32 + mi*16 + l16*4 + jj;
        int dv = wc*32 + ni*16 + l15;
        atomicAdd(cbase + dv*64 + e, cacc[mi][ni][jj]);
      }
}

// ---------------- combine (MFMA): out = q + sum_i (q@ctx_i)/(q.kc_i) --------
__global__ __launch_bounds__(256) void combine2(
    const unsigned short* __restrict__ qb,
    const float* __restrict__ ctxT,          // [3][64bh][64dv][64e]
    const float* __restrict__ kc,            // [3][64bh][64e]
    unsigned short* __restrict__ outp)
{
  __shared__ unsigned short sQ[128*64];
  __shared__ unsigned short sB[208*64];
  __shared__ float sS[128*3];
  const int tid = threadIdx.x, lane = tid & 63, wid = tid >> 6;
  const int l15 = lane & 15, l16 = lane >> 4;
  const int bh = blockIdx.y, b = bh >> 3, h = bh & 7;
  const int n0 = blockIdx.x * 128;
  const size_t qbase = ((size_t)b*N_ + n0)*C_ + h*64;

#pragma unroll
  for (int j = 0; j < 4; ++j) {
    int c = j*256 + tid;
    int row = c >> 3, c8 = c & 7;
    gload16(qb + qbase + (size_t)row*C_ + c8*8, sQ + (size_t)(j*256 + wid*64)*8);
  }
  for (int f = tid; f < 208*64; f += 256) {
    int col = f >> 6, e = f & 63;
    float val = 0.f;
    if (col < 192)
      val = ctxT[(((size_t)(col >> 6)*64 + bh)*64 + (col & 63))*64 + e];
    else if (col < 195)
      val = kc[((size_t)(col - 192)*64 + bh)*64 + e];
    sB[col*64 + e] = f2bf(val);
  }
  __syncthreads();

  f32_4 acc[2][13] = {};
#pragma unroll
  for (int ks = 0; ks < 2; ++ks) {
    bf16_8 af[2];
#pragma unroll
    for (int mi = 0; mi < 2; ++mi)
      af[mi] = *(const bf16_8*)&sQ[(wid*32 + mi*16 + l15)*64 + ks*32 + l16*8];
#pragma unroll
    for (int ni = 0; ni < 13; ++ni) {
      bf16_8 bfr = *(const bf16_8*)&sB[(ni*16 + l15)*64 + ks*32 + l16*8];
#pragma unroll
      for (int mi = 0; mi < 2; ++mi)
        acc[mi][ni] = __builtin_amdgcn_mfma_f32_16x16x32_bf16(af[mi], bfr, acc[mi][ni], 0, 0, 0);
    }
  }

  if (l15 < 3) {
#pragma unroll
    for (int mi = 0; mi < 2; ++mi)
#pragma unroll
      for (int jj = 0; jj < 4; ++jj)
        sS[(wid*32 + mi*16 + l16*4 + jj)*3 + l15] = acc[mi][12][jj];
  }
  __syncthreads();

#pragma unroll
  for (int mi = 0; mi < 2; ++mi) {
#pragma unroll
    for (int jj = 0; jj < 4; ++jj) {
      int r = wid*32 + mi*16 + l16*4 + jj;
      float inv[3];
#pragma unroll
      for (int i = 0; i < 3; ++i) inv[i] = 1.0f / sS[r*3 + i];
#pragma unroll
      for (int ni = 0; ni < 4; ++ni) {
        int dv = ni*16 + l15;
        float val = bf2f(sQ[r*64 + dv]);
#pragma unroll
        for (int i = 0; i < 3; ++i) val += acc[mi][i*4 + ni][jj] * inv[i];
        outp[qbase + (size_t)r*C_ + dv] = f2bf(val);
      }
    }
  }
}

// ---------------------------------------------------------------------------
extern "C" void kernel_launch(void* const* d_in, const int* in_sizes, int n_in,
                              void* d_out, int out_size, void* d_ws, size_t ws_size,
                              hipStream_t stream)
{
  const float* x  = (const float*)d_in[0];
  const float* y  = (const float*)d_in[1];
  const float* Wq = (const float*)d_in[2];
  const float* bq = (const float*)d_in[3];
  const float* Wk = (const float*)d_in[4];
  const float* bk = (const float*)d_in[5];
  const float* Wv = (const float*)d_in[6];
  const float* bv = (const float*)d_in[7];
  const float* Wp = (const float*)d_in[8];
  const float* bp = (const float*)d_in[9];
  float* out = (float*)d_out;
  char* ws = (char*)d_ws;

  const size_t SZ_BF = (size_t)M_ * C_ * 2;  // 32 MB bf16
  const size_t WCC   = (size_t)C_ * C_;      // 262144

  unsigned short* qb   = (unsigned short*)(ws);
  unsigned short* kb   = (unsigned short*)(ws + 1*SZ_BF);  // out_pre
  unsigned short* wq_b = (unsigned short*)(ws + 2*SZ_BF);
  unsigned short* wk_b = wq_b + WCC;        // [3][512][512]
  unsigned short* wv_b = wk_b + 3*WCC;
  unsigned short* wp_b = wv_b + 3*WCC;
  float* ctxT = (float*)(wp_b + WCC);
  float* kc   = ctxT + (size_t)3*64*64*64;

  cvt_f32_bf16<<<256, 256, 0, stream>>>(Wq, wq_b, (long)WCC/4);
  cvt_f32_bf16<<<256, 256, 0, stream>>>(Wk, wk_b, (long)3*WCC/4);
  cvt_f32_bf16<<<256, 256, 0, stream>>>(Wv, wv_b, (long)3*WCC/4);
  cvt_f32_bf16<<<256, 256, 0, stream>>>(Wp, wp_b, (long)WCC/4);

  hipMemsetAsync(ctxT, 0, ((size_t)3*64*64*64 + (size_t)3*64*64) * sizeof(float), stream);

  // q = softmax(x @ Wq^T + bq)
  gemm_all<1,0><<<dim3(M_/128, 4), 256, 0, stream>>>(x, wq_b, bq, qb);

  for (int i = 0; i < 3; ++i) {
    kvctx_kernel<<<dim3(64, 8), 256, 0, stream>>>(
        y + (size_t)i*M_*C_,
        wk_b + (size_t)i*WCC, wv_b + (size_t)i*WCC,
        bk + i*C_, bv + i*C_,
        ctxT + (size_t)i*64*64*64, kc + (size_t)i*64*64);
  }

  combine2<<<dim3(32, 64), 256, 0, stream>>>(qb, ctxT, kc, kb);
  gemm_all<0,1><<<dim3(M_/128, 4), 256, 0, stream>>>(kb, wp_b, bp, out);
}

// Round 6
// 676.290 us; speedup vs baseline: 1.0678x; 1.0006x over previous
//
#include <hip/hip_runtime.h>

// LinearCrossAttention: B=8, N=T=4096, C=512, H=8, d=64, 3 terms.
// R6: pre-convert x,y to bf16 (one BW pass); all GEMMs lean bf16 2-barrier
// loops with XOR swizzle; kvctx keeps fused softmax/ctx but bf16 A,
// 2 chunks/block, lower VGPR, higher occupancy.

#define B_  8
#define N_  4096
#define C_  512
#define T_  4096
#define H_  8
#define M_  (B_*N_)   // 32768

typedef __bf16 bf16_8 __attribute__((ext_vector_type(8)));
typedef float  f32_4  __attribute__((ext_vector_type(4)));

__device__ __forceinline__ unsigned short f2bf(float f) {
  unsigned u = __float_as_uint(f);
  unsigned r = 0x7FFFu + ((u >> 16) & 1u);
  return (unsigned short)((u + r) >> 16);
}
__device__ __forceinline__ float bf2f(unsigned short h) {
  return __uint_as_float(((unsigned)h) << 16);
}

__device__ __forceinline__ void gload16(const void* g, void* l) {
  __builtin_amdgcn_global_load_lds(
      (const __attribute__((address_space(1))) unsigned int*)g,
      (__attribute__((address_space(3))) unsigned int*)l, 16, 0, 0);
}

// ---------------- f32 -> bf16 conversion ------------------------------------
__global__ __launch_bounds__(256) void cvt_f32_bf16(
    const float* __restrict__ in, unsigned short* __restrict__ out, long n4)
{
  long i = (long)blockIdx.x * blockDim.x + threadIdx.x;
  long stride = (long)gridDim.x * blockDim.x;
  for (; i < n4; i += stride) {
    float4 v = ((const float4*)in)[i];
    ushort4 o;
    o.x = f2bf(v.x); o.y = f2bf(v.y); o.z = f2bf(v.z); o.w = f2bf(v.w);
    ((ushort4*)out)[i] = o;
  }
}

// ---------------- unified GEMM (bf16 A), 128x128 tile -----------------------
// EPI: 0 = f32 out + bias (final proj).  1 = softmax->bf16 (q path).
template<int EPI>
__global__ __launch_bounds__(256) void gemm_all(
    const unsigned short* __restrict__ A,    // [M][512] bf16
    const unsigned short* __restrict__ Bw,   // [N][512] bf16
    const float* __restrict__ bias,
    void* __restrict__ outp)
{
  __shared__ char smem[34816];
  unsigned short* sAh = (unsigned short*)smem;             // 16 KB
  unsigned short* sBw = (unsigned short*)(smem + 16384);   // 16 KB

  const int tid = threadIdx.x, lane = tid & 63, wid = tid >> 6;
  const int wr = wid >> 1, wc = wid & 1;
  const int l15 = lane & 15, l16 = lane >> 4;
  const size_t row0 = (size_t)blockIdx.x * 128;
  const int col0 = blockIdx.y * 128;

  f32_4 acc[4][4] = {};
  for (int k0 = 0; k0 < 512; k0 += 64) {
#pragma unroll
    for (int j = 0; j < 4; ++j) {
      int c = j*256 + tid, row = c >> 3, s = c & 7;
      gload16(A + (row0 + row)*512 + k0 + ((s ^ (row & 7)) << 3),
              smem + (size_t)(j*256 + wid*64)*16);
      gload16(Bw + (size_t)(col0 + row)*512 + k0 + ((s ^ (row & 7)) << 3),
              smem + 16384 + (size_t)(j*256 + wid*64)*16);
    }
    __syncthreads();
#pragma unroll
    for (int kk = 0; kk < 64; kk += 32) {
      bf16_8 af[4], bfr[4];
#pragma unroll
      for (int mi = 0; mi < 4; ++mi) {
        int r = wr*64 + mi*16 + l15;
        int ch = (kk >> 3) + l16;
        af[mi] = *(const bf16_8*)&sAh[r*64 + ((ch ^ (r & 7)) << 3)];
      }
#pragma unroll
      for (int ni = 0; ni < 4; ++ni) {
        int r = wc*64 + ni*16 + l15;
        int ch = (kk >> 3) + l16;
        bfr[ni] = *(const bf16_8*)&sBw[r*64 + ((ch ^ (r & 7)) << 3)];
      }
#pragma unroll
      for (int mi = 0; mi < 4; ++mi)
#pragma unroll
        for (int ni = 0; ni < 4; ++ni)
          acc[mi][ni] = __builtin_amdgcn_mfma_f32_16x16x32_bf16(af[mi], bfr[ni], acc[mi][ni], 0, 0, 0);
    }
    __syncthreads();
  }

  if constexpr (EPI == 0) {
    float* Cf = (float*)outp;
#pragma unroll
    for (int mi = 0; mi < 4; ++mi) {
      int rb = wr*64 + mi*16 + l16*4;
#pragma unroll
      for (int ni = 0; ni < 4; ++ni) {
        int col = col0 + wc*64 + ni*16 + l15;
        float bv = bias[col];
#pragma unroll
        for (int jj = 0; jj < 4; ++jj)
          Cf[(row0 + rb + jj)*512 + col] = acc[mi][ni][jj] + bv;
      }
    }
  } else {
    unsigned short* ob = (unsigned short*)outp;
    float bvv[4];
#pragma unroll
    for (int ni = 0; ni < 4; ++ni) bvv[ni] = bias[col0 + wc*64 + ni*16 + l15];
    unsigned short* sE = (unsigned short*)smem;   // 128 x pitch 136
#pragma unroll
    for (int mi = 0; mi < 4; ++mi) {
#pragma unroll
      for (int jj = 0; jj < 4; ++jj) {
        float x[4];
#pragma unroll
        for (int ni = 0; ni < 4; ++ni) x[ni] = acc[mi][ni][jj] + bvv[ni];
        float m = fmaxf(fmaxf(x[0], x[1]), fmaxf(x[2], x[3]));
#pragma unroll
        for (int o = 8; o; o >>= 1) m = fmaxf(m, __shfl_xor(m, o));
        float s = 0.f;
#pragma unroll
        for (int ni = 0; ni < 4; ++ni) { x[ni] = __expf(x[ni] - m); s += x[ni]; }
#pragma unroll
        for (int o = 8; o; o >>= 1) s += __shfl_xor(s, o);
        float inv = 1.0f / s;
        int r = wr*64 + mi*16 + l16*4 + jj;
#pragma unroll
        for (int ni = 0; ni < 4; ++ni)
          sE[r*136 + wc*64 + ni*16 + l15] = f2bf(x[ni] * inv);
      }
    }
    __syncthreads();
    int r = tid >> 1, seg = tid & 1;
    unsigned short* orow = ob + (row0 + r)*512 + col0 + seg*64;
#pragma unroll
    for (int u = 0; u < 8; ++u)
      *(uint4*)(orow + u*8) = *(const uint4*)&sE[r*136 + seg*64 + u*8];
  }
}

// ---------------- fused K/V GEMM + softmax + ctx/kc (bf16 A) ----------------
// grid (128, 8): block = 256 rows (2 chunks of 128) x head h.
__global__ __launch_bounds__(256) void kvctx_kernel(
    const unsigned short* __restrict__ yb,   // (B*T,512) bf16 for term i
    const unsigned short* __restrict__ Wk_b, // [512][512] bf16
    const unsigned short* __restrict__ Wv_b,
    const float* __restrict__ bk, const float* __restrict__ bv,
    float* __restrict__ ctxT,                // [64bh][64dv][64e] slice
    float* __restrict__ kc)                  // [64bh][64e] slice
{
  __shared__ char smem[34816];
  unsigned short* sAh = (unsigned short*)smem;             // 16 KB staging
  unsigned short* sBw = (unsigned short*)(smem + 16384);   // 16 KB
  unsigned short* sKT = (unsigned short*)smem;             // 64*136*2 = 17408
  unsigned short* sVT = (unsigned short*)(smem + 17408);   // 17408

  const int tid = threadIdx.x, lane = tid & 63, wid = tid >> 6;
  const int wr = wid >> 1, wc = wid & 1;
  const int l15 = lane & 15, l16 = lane >> 4;
  const int h = blockIdx.y;
  const int bx = blockIdx.x;                 // 0..127 (256-row blocks)
  const int b = bx >> 4;
  const int bh = b*8 + h;

  f32_4 cacc[2][2] = {};
  float kcp[4] = {0.f, 0.f, 0.f, 0.f};

  for (int chunk = 0; chunk < 2; ++chunk) {
    const size_t row0 = (size_t)bx*256 + chunk*128;
    f32_4 acc[4][4] = {};
    for (int k0 = 0; k0 < 512; k0 += 64) {
#pragma unroll
      for (int j = 0; j < 4; ++j) {
        int c = j*256 + tid, row = c >> 3, s = c & 7;
        gload16(yb + (row0 + row)*512 + k0 + ((s ^ (row & 7)) << 3),
                smem + (size_t)(j*256 + wid*64)*16);
        const unsigned short* wsrc = (row < 64)
            ? Wk_b + (size_t)(h*64 + row)*512
            : Wv_b + (size_t)(h*64 + row - 64)*512;
        gload16(wsrc + k0 + ((s ^ (row & 7)) << 3),
                smem + 16384 + (size_t)(j*256 + wid*64)*16);
      }
      __syncthreads();
#pragma unroll
      for (int kk = 0; kk < 64; kk += 32) {
        bf16_8 af[4], bfr[4];
#pragma unroll
        for (int mi = 0; mi < 4; ++mi) {
          int r = wr*64 + mi*16 + l15;
          int ch = (kk >> 3) + l16;
          af[mi] = *(const bf16_8*)&sAh[r*64 + ((ch ^ (r & 7)) << 3)];
        }
#pragma unroll
        for (int ni = 0; ni < 4; ++ni) {
          int r = wc*64 + ni*16 + l15;
          int ch = (kk >> 3) + l16;
          bfr[ni] = *(const bf16_8*)&sBw[r*64 + ((ch ^ (r & 7)) << 3)];
        }
#pragma unroll
        for (int mi = 0; mi < 4; ++mi)
#pragma unroll
          for (int ni = 0; ni < 4; ++ni)
            acc[mi][ni] = __builtin_amdgcn_mfma_f32_16x16x32_bf16(af[mi], bfr[ni], acc[mi][ni], 0, 0, 0);
      }
      __syncthreads();
    }

    // epilogue: K waves (wc==0) softmax + transposed store + kc partials;
    // V waves (wc==1) bias + transposed store.
    if (wc == 0) {
      float bkv[4];
#pragma unroll
      for (int ni = 0; ni < 4; ++ni) bkv[ni] = bk[h*64 + ni*16 + l15];
#pragma unroll
      for (int mi = 0; mi < 4; ++mi) {
#pragma unroll
        for (int jj = 0; jj < 4; ++jj) {
          float x[4];
#pragma unroll
          for (int ni = 0; ni < 4; ++ni) x[ni] = acc[mi][ni][jj] + bkv[ni];
          float m = fmaxf(fmaxf(x[0], x[1]), fmaxf(x[2], x[3]));
#pragma unroll
          for (int o = 8; o; o >>= 1) m = fmaxf(m, __shfl_xor(m, o));
          float s = 0.f;
#pragma unroll
          for (int ni = 0; ni < 4; ++ni) { x[ni] = __expf(x[ni] - m); s += x[ni]; }
#pragma unroll
          for (int o = 8; o; o >>= 1) s += __shfl_xor(s, o);
          float inv = 1.0f / s;
          int r = wr*64 + mi*16 + l16*4 + jj;
#pragma unroll
          for (int ni = 0; ni < 4; ++ni) {
            float kv = x[ni] * inv;
            kcp[ni] += kv;
            sKT[(ni*16 + l15)*136 + r] = f2bf(kv);
          }
        }
      }
    } else {
      float bvv[4];
#pragma unroll
      for (int ni = 0; ni < 4; ++ni) bvv[ni] = bv[h*64 + ni*16 + l15];
#pragma unroll
      for (int mi = 0; mi < 4; ++mi) {
#pragma unroll
        for (int jj = 0; jj < 4; ++jj) {
          int r = wr*64 + mi*16 + l16*4 + jj;
#pragma unroll
          for (int ni = 0; ni < 4; ++ni)
            sVT[(ni*16 + l15)*136 + r] = f2bf(acc[mi][ni][jj] + bvv[ni]);
        }
      }
    }
    __syncthreads();

    // ctx partial: cacc[e][dv] += sum over 128 t of k[t][e]*v[t][dv]
#pragma unroll
    for (int ks = 0; ks < 4; ++ks) {
      bf16_8 a2[2], b2[2];
#pragma unroll
      for (int mi = 0; mi < 2; ++mi)
        a2[mi] = *(const bf16_8*)&sKT[(wr*32 + mi*16 + l15)*136 + ks*32 + l16*8];
#pragma unroll
      for (int ni = 0; ni < 2; ++ni)
        b2[ni] = *(const bf16_8*)&sVT[(wc*32 + ni*16 + l15)*136 + ks*32 + l16*8];
#pragma unroll
      for (int mi = 0; mi < 2; ++mi)
#pragma unroll
        for (int ni = 0; ni < 2; ++ni)
          cacc[mi][ni] = __builtin_amdgcn_mfma_f32_16x16x32_bf16(a2[mi], b2[ni], cacc[mi][ni], 0, 0, 0);
    }
    __syncthreads();
  }

  if (wc == 0) {
#pragma unroll
    for (int ni = 0; ni < 4; ++ni) {
      float s = kcp[ni];
      s += __shfl_xor(s, 16);
      s += __shfl_xor(s, 32);
      if (l16 == 0) atomicAdd(kc + (size_t)bh*64 + ni*16 + l15, s);
    }
  }
  float* cbase = ctxT + (size_t)bh * 64*64;
#pragma unroll
  for (int mi = 0; mi < 2; ++mi)
#pragma unroll
    for (int ni = 0; ni < 2; ++ni)
#pragma unroll
      for (int jj = 0; jj < 4; ++jj) {
        int e  = wr*32 + mi*16 + l16*4 + jj;
        int dv = wc*32 + ni*16 + l15;
        atomicAdd(cbase + dv*64 + e, cacc[mi][ni][jj]);
      }
}

// ---------------- combine (MFMA): out = q + sum_i (q@ctx_i)/(q.kc_i) --------
__global__ __launch_bounds__(256) void combine2(
    const unsigned short* __restrict__ qb,
    const float* __restrict__ ctxT,          // [3][64bh][64dv][64e]
    const float* __restrict__ kc,            // [3][64bh][64e]
    unsigned short* __restrict__ outp)
{
  __shared__ unsigned short sQ[128*64];
  __shared__ unsigned short sB[208*64];
  __shared__ float sS[128*3];
  const int tid = threadIdx.x, lane = tid & 63, wid = tid >> 6;
  const int l15 = lane & 15, l16 = lane >> 4;
  const int bh = blockIdx.y, b = bh >> 3, h = bh & 7;
  const int n0 = blockIdx.x * 128;
  const size_t qbase = ((size_t)b*N_ + n0)*C_ + h*64;

#pragma unroll
  for (int j = 0; j < 4; ++j) {
    int c = j*256 + tid;
    int row = c >> 3, c8 = c & 7;
    gload16(qb + qbase + (size_t)row*C_ + c8*8, sQ + (size_t)(j*256 + wid*64)*8);
  }
  for (int f = tid; f < 208*64; f += 256) {
    int col = f >> 6, e = f & 63;
    float val = 0.f;
    if (col < 192)
      val = ctxT[(((size_t)(col >> 6)*64 + bh)*64 + (col & 63))*64 + e];
    else if (col < 195)
      val = kc[((size_t)(col - 192)*64 + bh)*64 + e];
    sB[col*64 + e] = f2bf(val);
  }
  __syncthreads();

  f32_4 acc[2][13] = {};
#pragma unroll
  for (int ks = 0; ks < 2; ++ks) {
    bf16_8 af[2];
#pragma unroll
    for (int mi = 0; mi < 2; ++mi)
      af[mi] = *(const bf16_8*)&sQ[(wid*32 + mi*16 + l15)*64 + ks*32 + l16*8];
#pragma unroll
    for (int ni = 0; ni < 13; ++ni) {
      bf16_8 bfr = *(const bf16_8*)&sB[(ni*16 + l15)*64 + ks*32 + l16*8];
#pragma unroll
      for (int mi = 0; mi < 2; ++mi)
        acc[mi][ni] = __builtin_amdgcn_mfma_f32_16x16x32_bf16(af[mi], bfr, acc[mi][ni], 0, 0, 0);
    }
  }

  if (l15 < 3) {
#pragma unroll
    for (int mi = 0; mi < 2; ++mi)
#pragma unroll
      for (int jj = 0; jj < 4; ++jj)
        sS[(wid*32 + mi*16 + l16*4 + jj)*3 + l15] = acc[mi][12][jj];
  }
  __syncthreads();

#pragma unroll
  for (int mi = 0; mi < 2; ++mi) {
#pragma unroll
    for (int jj = 0; jj < 4; ++jj) {
      int r = wid*32 + mi*16 + l16*4 + jj;
      float inv[3];
#pragma unroll
      for (int i = 0; i < 3; ++i) inv[i] = 1.0f / sS[r*3 + i];
#pragma unroll
      for (int ni = 0; ni < 4; ++ni) {
        int dv = ni*16 + l15;
        float val = bf2f(sQ[r*64 + dv]);
#pragma unroll
        for (int i = 0; i < 3; ++i) val += acc[mi][i*4 + ni][jj] * inv[i];
        outp[qbase + (size_t)r*C_ + dv] = f2bf(val);
      }
    }
  }
}

// ---------------------------------------------------------------------------
extern "C" void kernel_launch(void* const* d_in, const int* in_sizes, int n_in,
                              void* d_out, int out_size, void* d_ws, size_t ws_size,
                              hipStream_t stream)
{
  const float* x  = (const float*)d_in[0];
  const float* y  = (const float*)d_in[1];
  const float* Wq = (const float*)d_in[2];
  const float* bq = (const float*)d_in[3];
  const float* Wk = (const float*)d_in[4];
  const float* bk = (const float*)d_in[5];
  const float* Wv = (const float*)d_in[6];
  const float* bv = (const float*)d_in[7];
  const float* Wp = (const float*)d_in[8];
  const float* bp = (const float*)d_in[9];
  float* out = (float*)d_out;
  char* ws = (char*)d_ws;

  const size_t SZ_BF = (size_t)M_ * C_ * 2;  // 32 MB bf16
  const size_t WCC   = (size_t)C_ * C_;      // 262144

  unsigned short* xb   = (unsigned short*)(ws);
  unsigned short* yb   = (unsigned short*)(ws + 1*SZ_BF);  // 3 terms, 96 MB
  unsigned short* qb   = (unsigned short*)(ws + 4*SZ_BF);
  unsigned short* kb   = (unsigned short*)(ws + 5*SZ_BF);  // out_pre
  unsigned short* wq_b = (unsigned short*)(ws + 6*SZ_BF);
  unsigned short* wk_b = wq_b + WCC;        // [3][512][512]
  unsigned short* wv_b = wk_b + 3*WCC;
  unsigned short* wp_b = wv_b + 3*WCC;
  float* ctxT = (float*)(wp_b + WCC);
  float* kc   = ctxT + (size_t)3*64*64*64;

  cvt_f32_bf16<<<2048, 256, 0, stream>>>(x, xb, (long)M_*C_/4);
  cvt_f32_bf16<<<2048, 256, 0, stream>>>(y, yb, (long)3*M_*C_/4);
  cvt_f32_bf16<<<256, 256, 0, stream>>>(Wq, wq_b, (long)WCC/4);
  cvt_f32_bf16<<<256, 256, 0, stream>>>(Wk, wk_b, (long)3*WCC/4);
  cvt_f32_bf16<<<256, 256, 0, stream>>>(Wv, wv_b, (long)3*WCC/4);
  cvt_f32_bf16<<<256, 256, 0, stream>>>(Wp, wp_b, (long)WCC/4);

  hipMemsetAsync(ctxT, 0, ((size_t)3*64*64*64 + (size_t)3*64*64) * sizeof(float), stream);

  // q = softmax(x @ Wq^T + bq)
  gemm_all<1><<<dim3(M_/128, 4), 256, 0, stream>>>(xb, wq_b, bq, qb);

  for (int i = 0; i < 3; ++i) {
    kvctx_kernel<<<dim3(128, 8), 256, 0, stream>>>(
        yb + (size_t)i*M_*C_,
        wk_b + (size_t)i*WCC, wv_b + (size_t)i*WCC,
        bk + i*C_, bv + i*C_,
        ctxT + (size_t)i*64*64*64, kc + (size_t)i*64*64);
  }

  combine2<<<dim3(32, 64), 256, 0, stream>>>(qb, ctxT, kc, kb);
  gemm_all<0><<<dim3(M_/128, 4), 256, 0, stream>>>(kb, wp_b, bp, out);
}

// Round 7
// 514.044 us; speedup vs baseline: 1.4048x; 1.3156x over previous
//
#include <hip/hip_runtime.h>

// LinearCrossAttention: B=8, N=T=4096, C=512, H=8, d=64, 3 terms.
// R7: 2-phase double-buffered GEMM loops (counted-vmcnt, raw barriers);
// ctx/kc atomics replaced by per-block partials + reduce kernel;
// all 3 kvctx terms batched in one launch.

#define B_  8
#define N_  4096
#define C_  512
#define T_  4096
#define H_  8
#define M_  (B_*N_)   // 32768

typedef __bf16 bf16_8 __attribute__((ext_vector_type(8)));
typedef float  f32_4  __attribute__((ext_vector_type(4)));

__device__ __forceinline__ unsigned short f2bf(float f) {
  unsigned u = __float_as_uint(f);
  unsigned r = 0x7FFFu + ((u >> 16) & 1u);
  return (unsigned short)((u + r) >> 16);
}
__device__ __forceinline__ float bf2f(unsigned short h) {
  return __uint_as_float(((unsigned)h) << 16);
}

__device__ __forceinline__ void gload16(const void* g, void* l) {
  __builtin_amdgcn_global_load_lds(
      (const __attribute__((address_space(1))) unsigned int*)g,
      (__attribute__((address_space(3))) unsigned int*)l, 16, 0, 0);
}

// ---------------- f32 -> bf16 conversion ------------------------------------
__global__ __launch_bounds__(256) void cvt_f32_bf16(
    const float* __restrict__ in, unsigned short* __restrict__ out, long n4)
{
  long i = (long)blockIdx.x * blockDim.x + threadIdx.x;
  long stride = (long)gridDim.x * blockDim.x;
  for (; i < n4; i += stride) {
    float4 v = ((const float4*)in)[i];
    ushort4 o;
    o.x = f2bf(v.x); o.y = f2bf(v.y); o.z = f2bf(v.z); o.w = f2bf(v.w);
    ((ushort4*)out)[i] = o;
  }
}

// ---------------- unified GEMM (bf16 A), 128x128 tile, 2-phase dbuf ---------
// EPI: 0 = f32 out + bias (final proj).  1 = softmax->bf16 (q path).
template<int EPI>
__global__ __launch_bounds__(256) void gemm_all(
    const unsigned short* __restrict__ A,    // [M][512] bf16
    const unsigned short* __restrict__ Bw,   // [N][512] bf16
    const float* __restrict__ bias,
    void* __restrict__ outp)
{
  __shared__ char smem[65536];   // bufA[2]@0,16384 ; bufB[2]@32768,49152

  const int tid = threadIdx.x, lane = tid & 63, wid = tid >> 6;
  const int wr = wid >> 1, wc = wid & 1;
  const int l15 = lane & 15, l16 = lane >> 4;
  const size_t row0 = (size_t)blockIdx.x * 128;
  const int col0 = blockIdx.y * 128;

  f32_4 acc[4][4] = {};

  auto stage = [&](int k0, int bsel) {
#pragma unroll
    for (int j = 0; j < 4; ++j) {
      int cc = j*256 + tid, row = cc >> 3, s = cc & 7;
      gload16(A + (row0 + row)*512 + k0 + ((s ^ (row & 7)) << 3),
              smem + bsel*16384 + (size_t)(j*256 + wid*64)*16);
      gload16(Bw + (size_t)(col0 + row)*512 + k0 + ((s ^ (row & 7)) << 3),
              smem + 32768 + bsel*16384 + (size_t)(j*256 + wid*64)*16);
    }
  };

  stage(0, 0);
  asm volatile("s_waitcnt vmcnt(0)" ::: "memory");
  __builtin_amdgcn_s_barrier();
  for (int t = 0; t < 8; ++t) {
    int cur = t & 1;
    if (t < 7) stage((t+1)*64, cur ^ 1);
    const unsigned short* sA = (const unsigned short*)(smem + (size_t)cur*16384);
    const unsigned short* sB = (const unsigned short*)(smem + 32768 + (size_t)cur*16384);
#pragma unroll
    for (int kk = 0; kk < 64; kk += 32) {
      bf16_8 af[4], bfr[4];
#pragma unroll
      for (int mi = 0; mi < 4; ++mi) {
        int r = wr*64 + mi*16 + l15;
        int ch = (kk >> 3) + l16;
        af[mi] = *(const bf16_8*)&sA[r*64 + ((ch ^ (r & 7)) << 3)];
      }
#pragma unroll
      for (int ni = 0; ni < 4; ++ni) {
        int r = wc*64 + ni*16 + l15;
        int ch = (kk >> 3) + l16;
        bfr[ni] = *(const bf16_8*)&sB[r*64 + ((ch ^ (r & 7)) << 3)];
      }
#pragma unroll
      for (int mi = 0; mi < 4; ++mi)
#pragma unroll
        for (int ni = 0; ni < 4; ++ni)
          acc[mi][ni] = __builtin_amdgcn_mfma_f32_16x16x32_bf16(af[mi], bfr[ni], acc[mi][ni], 0, 0, 0);
    }
    if (t < 7) asm volatile("s_waitcnt vmcnt(0)" ::: "memory");
    __builtin_amdgcn_s_barrier();
  }

  if constexpr (EPI == 0) {
    float* Cf = (float*)outp;
#pragma unroll
    for (int mi = 0; mi < 4; ++mi) {
      int rb = wr*64 + mi*16 + l16*4;
#pragma unroll
      for (int ni = 0; ni < 4; ++ni) {
        int col = col0 + wc*64 + ni*16 + l15;
        float bv = bias[col];
#pragma unroll
        for (int jj = 0; jj < 4; ++jj)
          Cf[(row0 + rb + jj)*512 + col] = acc[mi][ni][jj] + bv;
      }
    }
  } else {
    unsigned short* ob = (unsigned short*)outp;
    float bvv[4];
#pragma unroll
    for (int ni = 0; ni < 4; ++ni) bvv[ni] = bias[col0 + wc*64 + ni*16 + l15];
    unsigned short* sE = (unsigned short*)smem;   // 128 x pitch 136
#pragma unroll
    for (int mi = 0; mi < 4; ++mi) {
#pragma unroll
      for (int jj = 0; jj < 4; ++jj) {
        float x[4];
#pragma unroll
        for (int ni = 0; ni < 4; ++ni) x[ni] = acc[mi][ni][jj] + bvv[ni];
        float m = fmaxf(fmaxf(x[0], x[1]), fmaxf(x[2], x[3]));
#pragma unroll
        for (int o = 8; o; o >>= 1) m = fmaxf(m, __shfl_xor(m, o));
        float s = 0.f;
#pragma unroll
        for (int ni = 0; ni < 4; ++ni) { x[ni] = __expf(x[ni] - m); s += x[ni]; }
#pragma unroll
        for (int o = 8; o; o >>= 1) s += __shfl_xor(s, o);
        float inv = 1.0f / s;
        int r = wr*64 + mi*16 + l16*4 + jj;
#pragma unroll
        for (int ni = 0; ni < 4; ++ni)
          sE[r*136 + wc*64 + ni*16 + l15] = f2bf(x[ni] * inv);
      }
    }
    asm volatile("s_waitcnt lgkmcnt(0)" ::: "memory");
    __builtin_amdgcn_s_barrier();
    int r = tid >> 1, seg = tid & 1;
    unsigned short* orow = ob + (row0 + r)*512 + col0 + seg*64;
#pragma unroll
    for (int u = 0; u < 8; ++u)
      *(uint4*)(orow + u*8) = *(const uint4*)&sE[r*136 + seg*64 + u*8];
  }
}

// ---------------- fused K/V GEMM + softmax + ctx/kc partials ----------------
// grid (64, 8, 3): bx = 512-row slab (4 chunks of 128), h = head, z = term.
__global__ __launch_bounds__(256) void kvctx_kernel(
    const unsigned short* __restrict__ yb_all, // [3][32768][512] bf16
    const unsigned short* __restrict__ wk_all, // [3][512][512] bf16
    const unsigned short* __restrict__ wv_all,
    const float* __restrict__ bk_all,          // [3][512]
    const float* __restrict__ bv_all,
    float* __restrict__ part,                  // [3*64][8][4096]
    float* __restrict__ kcp)                   // [3*64][8][2][64]
{
  __shared__ char smem[65536];
  unsigned short* sKT = (unsigned short*)smem;             // 64*136*2
  unsigned short* sVT = (unsigned short*)(smem + 17408);

  const int tid = threadIdx.x, lane = tid & 63, wid = tid >> 6;
  const int wr = wid >> 1, wc = wid & 1;
  const int l15 = lane & 15, l16 = lane >> 4;
  const int h = blockIdx.y, bx = blockIdx.x, i = blockIdx.z;
  const int b = bx >> 3, sub = bx & 7;
  const int bh = b*8 + h;

  const unsigned short* yb = yb_all + (size_t)i*M_*512;
  const unsigned short* Wk_b = wk_all + (size_t)i*512*512 + (size_t)h*64*512;
  const unsigned short* Wv_b = wv_all + (size_t)i*512*512 + (size_t)h*64*512;
  const float* bk = bk_all + i*512 + h*64;
  const float* bv = bv_all + i*512 + h*64;

  f32_4 cacc[2][2] = {};
  float kcp_r[4] = {0.f, 0.f, 0.f, 0.f};

  for (int chunk = 0; chunk < 4; ++chunk) {
    const size_t row0 = (size_t)bx*512 + chunk*128;
    f32_4 acc[4][4] = {};

    auto stage = [&](int k0, int bsel) {
#pragma unroll
      for (int j = 0; j < 4; ++j) {
        int cc = j*256 + tid, row = cc >> 3, s = cc & 7;
        gload16(yb + (row0 + row)*512 + k0 + ((s ^ (row & 7)) << 3),
                smem + bsel*16384 + (size_t)(j*256 + wid*64)*16);
        const unsigned short* wsrc = (j < 2)
            ? Wk_b + (size_t)row*512
            : Wv_b + (size_t)(row - 64)*512;
        gload16(wsrc + k0 + ((s ^ (row & 7)) << 3),
                smem + 32768 + bsel*16384 + (size_t)(j*256 + wid*64)*16);
      }
    };

    stage(0, 0);
    asm volatile("s_waitcnt vmcnt(0)" ::: "memory");
    __builtin_amdgcn_s_barrier();
    for (int t = 0; t < 8; ++t) {
      int cur = t & 1;
      if (t < 7) stage((t+1)*64, cur ^ 1);
      const unsigned short* sA = (const unsigned short*)(smem + (size_t)cur*16384);
      const unsigned short* sB = (const unsigned short*)(smem + 32768 + (size_t)cur*16384);
#pragma unroll
      for (int kk = 0; kk < 64; kk += 32) {
        bf16_8 af[4], bfr[4];
#pragma unroll
        for (int mi = 0; mi < 4; ++mi) {
          int r = wr*64 + mi*16 + l15;
          int ch = (kk >> 3) + l16;
          af[mi] = *(const bf16_8*)&sA[r*64 + ((ch ^ (r & 7)) << 3)];
        }
#pragma unroll
        for (int ni = 0; ni < 4; ++ni) {
          int r = wc*64 + ni*16 + l15;
          int ch = (kk >> 3) + l16;
          bfr[ni] = *(const bf16_8*)&sB[r*64 + ((ch ^ (r & 7)) << 3)];
        }
#pragma unroll
        for (int mi = 0; mi < 4; ++mi)
#pragma unroll
          for (int ni = 0; ni < 4; ++ni)
            acc[mi][ni] = __builtin_amdgcn_mfma_f32_16x16x32_bf16(af[mi], bfr[ni], acc[mi][ni], 0, 0, 0);
      }
      if (t < 7) asm volatile("s_waitcnt vmcnt(0)" ::: "memory");
      __builtin_amdgcn_s_barrier();
    }

    // epilogue: K waves (wc==0) softmax + K^T store + kc partials;
    // V waves (wc==1) bias + V^T store.
    if (wc == 0) {
      float bkv[4];
#pragma unroll
      for (int ni = 0; ni < 4; ++ni) bkv[ni] = bk[ni*16 + l15];
#pragma unroll
      for (int mi = 0; mi < 4; ++mi) {
#pragma unroll
        for (int jj = 0; jj < 4; ++jj) {
          float x[4];
#pragma unroll
          for (int ni = 0; ni < 4; ++ni) x[ni] = acc[mi][ni][jj] + bkv[ni];
          float m = fmaxf(fmaxf(x[0], x[1]), fmaxf(x[2], x[3]));
#pragma unroll
          for (int o = 8; o; o >>= 1) m = fmaxf(m, __shfl_xor(m, o));
          float s = 0.f;
#pragma unroll
          for (int ni = 0; ni < 4; ++ni) { x[ni] = __expf(x[ni] - m); s += x[ni]; }
#pragma unroll
          for (int o = 8; o; o >>= 1) s += __shfl_xor(s, o);
          float inv = 1.0f / s;
          int r = wr*64 + mi*16 + l16*4 + jj;
#pragma unroll
          for (int ni = 0; ni < 4; ++ni) {
            float kv = x[ni] * inv;
            kcp_r[ni] += kv;
            sKT[(ni*16 + l15)*136 + r] = f2bf(kv);
          }
        }
      }
    } else {
      float bvv[4];
#pragma unroll
      for (int ni = 0; ni < 4; ++ni) bvv[ni] = bv[ni*16 + l15];
#pragma unroll
      for (int mi = 0; mi < 4; ++mi) {
#pragma unroll
        for (int jj = 0; jj < 4; ++jj) {
          int r = wr*64 + mi*16 + l16*4 + jj;
#pragma unroll
          for (int ni = 0; ni < 4; ++ni)
            sVT[(ni*16 + l15)*136 + r] = f2bf(acc[mi][ni][jj] + bvv[ni]);
        }
      }
    }
    asm volatile("s_waitcnt lgkmcnt(0)" ::: "memory");
    __builtin_amdgcn_s_barrier();

    // ctx partial: cacc[e][dv] += sum over 128 t of k[t][e]*v[t][dv]
#pragma unroll
    for (int ks = 0; ks < 4; ++ks) {
      bf16_8 a2[2], b2[2];
#pragma unroll
      for (int mi = 0; mi < 2; ++mi)
        a2[mi] = *(const bf16_8*)&sKT[(wr*32 + mi*16 + l15)*136 + ks*32 + l16*8];
#pragma unroll
      for (int ni = 0; ni < 2; ++ni)
        b2[ni] = *(const bf16_8*)&sVT[(wc*32 + ni*16 + l15)*136 + ks*32 + l16*8];
#pragma unroll
      for (int mi = 0; mi < 2; ++mi)
#pragma unroll
        for (int ni = 0; ni < 2; ++ni)
          cacc[mi][ni] = __builtin_amdgcn_mfma_f32_16x16x32_bf16(a2[mi], b2[ni], cacc[mi][ni], 0, 0, 0);
    }
    __builtin_amdgcn_s_barrier();
  }

  // write partials (no atomics)
  const size_t slot = (size_t)(i*64 + bh)*8 + sub;
  if (wc == 0) {
#pragma unroll
    for (int ni = 0; ni < 4; ++ni) {
      float s = kcp_r[ni];
      s += __shfl_xor(s, 16);
      s += __shfl_xor(s, 32);
      if (l16 == 0) kcp[(slot*2 + wr)*64 + ni*16 + l15] = s;
    }
  }
  float* pb = part + slot*4096;
#pragma unroll
  for (int mi = 0; mi < 2; ++mi)
#pragma unroll
    for (int ni = 0; ni < 2; ++ni) {
      int e0 = wr*32 + mi*16 + l16*4;
      int dv = wc*32 + ni*16 + l15;
      *(f32_4*)&pb[dv*64 + e0] = cacc[mi][ni];
    }
}

// ---------------- reduce partials -> ctxT, kc -------------------------------
__global__ __launch_bounds__(256) void ctx_reduce(
    const float* __restrict__ part,   // [192][8][4096]
    const float* __restrict__ kcp,    // [192][8][2][64]
    float* __restrict__ ctxT,         // [192][4096]
    float* __restrict__ kc)           // [192][64]
{
  int g = blockIdx.x;
  const float* p = part + (size_t)g*8*4096;
  float* o = ctxT + (size_t)g*4096;
#pragma unroll
  for (int jj = 0; jj < 4; ++jj) {
    int j = (jj*256 + threadIdx.x)*4;
    f32_4 s = {};
#pragma unroll
    for (int r = 0; r < 8; ++r) {
      f32_4 v = *(const f32_4*)&p[(size_t)r*4096 + j];
      s[0] += v[0]; s[1] += v[1]; s[2] += v[2]; s[3] += v[3];
    }
    *(f32_4*)&o[j] = s;
  }
  if (threadIdx.x < 64) {
    const float* pk = kcp + (size_t)g*16*64;
    float s = 0.f;
#pragma unroll
    for (int r = 0; r < 16; ++r) s += pk[r*64 + threadIdx.x];
    kc[(size_t)g*64 + threadIdx.x] = s;
  }
}

// ---------------- combine (MFMA): out = q + sum_i (q@ctx_i)/(q.kc_i) --------
__global__ __launch_bounds__(256) void combine2(
    const unsigned short* __restrict__ qb,
    const float* __restrict__ ctxT,          // [3][64bh][64dv][64e]
    const float* __restrict__ kc,            // [3][64bh][64e]
    unsigned short* __restrict__ outp)
{
  __shared__ unsigned short sQ[128*64];
  __shared__ unsigned short sB[208*64];
  __shared__ float sS[128*3];
  const int tid = threadIdx.x, lane = tid & 63, wid = tid >> 6;
  const int l15 = lane & 15, l16 = lane >> 4;
  const int bh = blockIdx.y, b = bh >> 3, h = bh & 7;
  const int n0 = blockIdx.x * 128;
  const size_t qbase = ((size_t)b*N_ + n0)*C_ + h*64;

#pragma unroll
  for (int j = 0; j < 4; ++j) {
    int c = j*256 + tid;
    int row = c >> 3, c8 = c & 7;
    gload16(qb + qbase + (size_t)row*C_ + c8*8, sQ + (size_t)(j*256 + wid*64)*8);
  }
  for (int f = tid; f < 208*64; f += 256) {
    int col = f >> 6, e = f & 63;
    float val = 0.f;
    if (col < 192)
      val = ctxT[(((size_t)(col >> 6)*64 + bh)*64 + (col & 63))*64 + e];
    else if (col < 195)
      val = kc[((size_t)(col - 192)*64 + bh)*64 + e];
    sB[col*64 + e] = f2bf(val);
  }
  __syncthreads();

  f32_4 acc[2][13] = {};
#pragma unroll
  for (int ks = 0; ks < 2; ++ks) {
    bf16_8 af[2];
#pragma unroll
    for (int mi = 0; mi < 2; ++mi)
      af[mi] = *(const bf16_8*)&sQ[(wid*32 + mi*16 + l15)*64 + ks*32 + l16*8];
#pragma unroll
    for (int ni = 0; ni < 13; ++ni) {
      bf16_8 bfr = *(const bf16_8*)&sB[(ni*16 + l15)*64 + ks*32 + l16*8];
#pragma unroll
      for (int mi = 0; mi < 2; ++mi)
        acc[mi][ni] = __builtin_amdgcn_mfma_f32_16x16x32_bf16(af[mi], bfr, acc[mi][ni], 0, 0, 0);
    }
  }

  if (l15 < 3) {
#pragma unroll
    for (int mi = 0; mi < 2; ++mi)
#pragma unroll
      for (int jj = 0; jj < 4; ++jj)
        sS[(wid*32 + mi*16 + l16*4 + jj)*3 + l15] = acc[mi][12][jj];
  }
  __syncthreads();

#pragma unroll
  for (int mi = 0; mi < 2; ++mi) {
#pragma unroll
    for (int jj = 0; jj < 4; ++jj) {
      int r = wid*32 + mi*16 + l16*4 + jj;
      float inv[3];
#pragma unroll
      for (int i = 0; i < 3; ++i) inv[i] = 1.0f / sS[r*3 + i];
#pragma unroll
      for (int ni = 0; ni < 4; ++ni) {
        int dv = ni*16 + l15;
        float val = bf2f(sQ[r*64 + dv]);
#pragma unroll
        for (int i = 0; i < 3; ++i) val += acc[mi][i*4 + ni][jj] * inv[i];
        outp[qbase + (size_t)r*C_ + dv] = f2bf(val);
      }
    }
  }
}

// ---------------------------------------------------------------------------
extern "C" void kernel_launch(void* const* d_in, const int* in_sizes, int n_in,
                              void* d_out, int out_size, void* d_ws, size_t ws_size,
                              hipStream_t stream)
{
  const float* x  = (const float*)d_in[0];
  const float* y  = (const float*)d_in[1];
  const float* Wq = (const float*)d_in[2];
  const float* bq = (const float*)d_in[3];
  const float* Wk = (const float*)d_in[4];
  const float* bk = (const float*)d_in[5];
  const float* Wv = (const float*)d_in[6];
  const float* bv = (const float*)d_in[7];
  const float* Wp = (const float*)d_in[8];
  const float* bp = (const float*)d_in[9];
  float* out = (float*)d_out;
  char* ws = (char*)d_ws;

  const size_t SZ_BF = (size_t)M_ * C_ * 2;  // 32 MB bf16
  const size_t WCC   = (size_t)C_ * C_;      // 262144

  unsigned short* xb   = (unsigned short*)(ws);
  unsigned short* yb   = (unsigned short*)(ws + 1*SZ_BF);  // 3 terms, 96 MB
  unsigned short* qb   = (unsigned short*)(ws + 4*SZ_BF);
  unsigned short* kb   = (unsigned short*)(ws + 5*SZ_BF);  // partials, then out_pre
  unsigned short* wq_b = (unsigned short*)(ws + 6*SZ_BF);
  unsigned short* wk_b = wq_b + WCC;        // [3][512][512]
  unsigned short* wv_b = wk_b + 3*WCC;
  unsigned short* wp_b = wv_b + 3*WCC;
  float* ctxT = (float*)(wp_b + WCC);
  float* kc   = ctxT + (size_t)3*64*64*64;

  float* part  = (float*)kb;                       // 192*8*4096*4 = 25.2 MB
  float* kcpar = part + (size_t)192*8*4096;        // 192*16*64*4  = 786 KB

  cvt_f32_bf16<<<2048, 256, 0, stream>>>(x, xb, (long)M_*C_/4);
  cvt_f32_bf16<<<2048, 256, 0, stream>>>(y, yb, (long)3*M_*C_/4);
  cvt_f32_bf16<<<256, 256, 0, stream>>>(Wq, wq_b, (long)WCC/4);
  cvt_f32_bf16<<<256, 256, 0, stream>>>(Wk, wk_b, (long)3*WCC/4);
  cvt_f32_bf16<<<256, 256, 0, stream>>>(Wv, wv_b, (long)3*WCC/4);
  cvt_f32_bf16<<<256, 256, 0, stream>>>(Wp, wp_b, (long)WCC/4);

  // q = softmax(x @ Wq^T + bq)
  gemm_all<1><<<dim3(M_/128, 4), 256, 0, stream>>>(xb, wq_b, bq, qb);

  // all 3 terms in one launch; partials instead of atomics
  kvctx_kernel<<<dim3(64, 8, 3), 256, 0, stream>>>(
      yb, wk_b, wv_b, bk, bv, part, kcpar);
  ctx_reduce<<<192, 256, 0, stream>>>(part, kcpar, ctxT, kc);

  combine2<<<dim3(32, 64), 256, 0, stream>>>(qb, ctxT, kc, kb);
  gemm_all<0><<<dim3(M_/128, 4), 256, 0, stream>>>(kb, wp_b, bp, out);
}